// Round 1
// baseline (889.623 us; speedup 1.0000x reference)
//
#include <hip/hip_runtime.h>

#define CIN 96
#define COUT 192
#define SW 4

#define BM 64          // windows (output rows) per block
#define BKC 32         // K chunk staged per sync
#define A_STRIDE 100   // 64x100 fp32 = 25.6 KB; row stride 100 -> 2-way bank alias (free)
#define W_STRIDE 200   // 32x200 fp32 = 25.6 KB

// Compute window metadata for window m by scanning the (tiny, B<=8) lengths
// array. Wave-uniform loop -> scalar loads; avoids any workspace dependency.
// Returns M (total number of windows).
__device__ __forceinline__ long long win_meta(const int* __restrict__ lengths, int B,
                                              long long m, long long* start_out,
                                              int* cnt_out, int* batch_out) {
  long long off = 0, woff = 0;
  long long start = 0;
  int cnt = 0, bf = 0;
  for (int i = 0; i < B; ++i) {
    long long L = lengths[i];
    long long nw = (L + (SW - 1)) >> 2;
    if (m >= woff && m < woff + nw) {
      long long st = off + (m - woff) * SW;
      long long rem = off + L - st;
      start = st;
      cnt = (int)(rem < (long long)SW ? rem : (long long)SW);
      bf = i;
    }
    off += L;
    woff += nw;
  }
  *start_out = start;
  *cnt_out = cnt;
  *batch_out = bf;
  return woff;
}

// lengths_down (as float) and offset_down (cumsum, as float). Values <= 262147
// are exactly representable in fp32.
__global__ void meta_kernel(const int* __restrict__ lengths, int B,
                            float* __restrict__ out) {
  if (blockIdx.x != 0 || threadIdx.x != 0) return;
  long long M = 0;
  for (int i = 0; i < B; ++i) M += ((long long)lengths[i] + (SW - 1)) >> 2;
  long long o4 = M * (long long)(COUT + 3 + 1 + 1);  // 197*M
  long long cum = 0;
  for (int i = 0; i < B; ++i) {
    long long nw = ((long long)lengths[i] + (SW - 1)) >> 2;
    out[o4 + i] = (float)nw;
    cum += nw;
    out[o4 + B + i] = (float)cum;
  }
}

// coord_down (M,3), batch_down (M), scores_down (M). One thread per window.
__global__ void pool_small_kernel(const float* __restrict__ coord,
                                  const float* __restrict__ scores,
                                  const int* __restrict__ lengths, int B,
                                  float* __restrict__ out) {
  long long m = (long long)blockIdx.x * blockDim.x + threadIdx.x;
  long long start; int cnt, bf;
  long long M = win_meta(lengths, B, m, &start, &cnt, &bf);
  if (m >= M) return;
  float cx = 0.f, cy = 0.f, cz = 0.f, s = 0.f;
  for (int p = 0; p < cnt; ++p) {
    long long q = start + p;
    cx += coord[q * 3 + 0];
    cy += coord[q * 3 + 1];
    cz += coord[q * 3 + 2];
    s += scores[q];
  }
  float inv = 1.0f / (float)cnt;
  long long o1 = M * (long long)COUT;
  long long o2 = o1 + M * 3;
  long long o3 = o2 + M;
  out[o1 + m * 3 + 0] = cx * inv;
  out[o1 + m * 3 + 1] = cy * inv;
  out[o1 + m * 3 + 2] = cz * inv;
  out[o2 + m] = (float)bf;   // batch id, exact in fp32
  out[o3 + m] = s * inv;
}

// Fused windowed-mean-pool + GEMM (M,96)x(96,192) + bias + ReLU.
// Block: 256 threads = 16x16; each thread owns a 4-row x 12-col register tile.
// LDS: A 25.6 KB + Wchunk 25.6 KB + misc ~1.5 KB = 52.7 KB -> 3 blocks/CU.
__global__ __launch_bounds__(256) void gemm_kernel(
    const float* __restrict__ feat, const float* __restrict__ W,
    const float* __restrict__ bias, const int* __restrict__ lengths, int B,
    float* __restrict__ out) {
  __shared__ float A_lds[BM * A_STRIDE];
  __shared__ float W_lds[BKC * W_STRIDE];
  __shared__ float b_lds[COUT];
  __shared__ int s_start[BM];
  __shared__ int s_cnt[BM];
  __shared__ float s_inv[BM];

  const int tid = threadIdx.x;
  const long long m0 = (long long)blockIdx.x * BM;

  // Per-window metadata (threads 0..63 publish; all threads learn M).
  long long start; int cnt, bf;
  const long long M = win_meta(lengths, B, m0 + (tid & (BM - 1)), &start, &cnt, &bf);
  if (tid < BM) {
    s_start[tid] = (int)start;       // N < 2^31, fits int
    s_cnt[tid] = cnt;
    s_inv[tid] = cnt ? 1.0f / (float)cnt : 0.0f;
  }
  if (tid < COUT) b_lds[tid] = bias[tid];
  __syncthreads();

  // Pooled A-tile load: 64*96 = 6144 values, 24 per thread. Consecutive tid
  // -> consecutive channel c -> coalesced global reads of contiguous rows.
  #pragma unroll
  for (int i = 0; i < 24; ++i) {
    int v = tid + 256 * i;
    int ml = v / CIN;
    int c = v - ml * CIN;
    int cw = s_cnt[ml];
    const float* fp = feat + (long long)s_start[ml] * CIN + c;
    float s = 0.f;
    for (int p = 0; p < cw; ++p) s += fp[p * CIN];
    A_lds[ml * A_STRIDE + c] = s * s_inv[ml];  // mean = sum * (1/cnt), like ref
  }

  const int tx = tid & 15;       // col group: cols tx*12 .. tx*12+11
  const int ty = tid >> 4;       // row group: rows ty*4 .. ty*4+3
  const int row0 = ty * 4;
  const int col0 = tx * 12;

  float acc[4][12];
  #pragma unroll
  for (int i = 0; i < 4; ++i)
    #pragma unroll
    for (int j = 0; j < 12; ++j) acc[i][j] = 0.f;

  for (int kc = 0; kc < CIN; kc += BKC) {
    __syncthreads();  // A/meta ready (kc=0); W_lds no longer read (kc>0)
    // Stage W[kc..kc+31][0..191]: 1536 float4, 6 per thread, coalesced.
    #pragma unroll
    for (int i = 0; i < 6; ++i) {
      int f = tid + 256 * i;
      int kk = f / 48;          // 48 float4 per K-row
      int cg = f - kk * 48;
      *(float4*)&W_lds[kk * W_STRIDE + cg * 4] =
          *(const float4*)&W[(long long)(kc + kk) * COUT + cg * 4];
    }
    __syncthreads();

    #pragma unroll 8
    for (int kk = 0; kk < BKC; ++kk) {
      float a0 = A_lds[(row0 + 0) * A_STRIDE + kc + kk];
      float a1 = A_lds[(row0 + 1) * A_STRIDE + kc + kk];
      float a2 = A_lds[(row0 + 2) * A_STRIDE + kc + kk];
      float a3 = A_lds[(row0 + 3) * A_STRIDE + kc + kk];
      const float* wr = &W_lds[kk * W_STRIDE + col0];
      #pragma unroll
      for (int j = 0; j < 12; ++j) {
        float bw = wr[j];
        acc[0][j] = fmaf(a0, bw, acc[0][j]);
        acc[1][j] = fmaf(a1, bw, acc[1][j]);
        acc[2][j] = fmaf(a2, bw, acc[2][j]);
        acc[3][j] = fmaf(a3, bw, acc[3][j]);
      }
    }
  }

  // Epilogue: bias + ReLU, guarded by true M. 12 contiguous floats per row.
  #pragma unroll
  for (int i = 0; i < 4; ++i) {
    long long m = m0 + row0 + i;
    if (m < M) {
      float* op = out + m * (long long)COUT + col0;
      #pragma unroll
      for (int j = 0; j < 12; ++j) {
        float x = acc[i][j] + b_lds[col0 + j];
        op[j] = x > 0.f ? x : 0.f;
      }
    }
  }
}

extern "C" void kernel_launch(void* const* d_in, const int* in_sizes, int n_in,
                              void* d_out, int out_size, void* d_ws, size_t ws_size,
                              hipStream_t stream) {
  const float* feat    = (const float*)d_in[0];
  const float* coord   = (const float*)d_in[1];
  const float* scores  = (const float*)d_in[2];
  const float* W       = (const float*)d_in[3];
  const float* bias    = (const float*)d_in[4];
  const int*   lengths = (const int*)d_in[5];
  // d_in[6] = batch (int) — unused; reconstructed from lengths.
  float* out = (float*)d_out;

  const int N = in_sizes[2];   // number of points (scores is (N,))
  const int B = in_sizes[5];   // number of batches
  // Data-independent upper bound: sum ceil(L/4) <= N/4 + B.
  const int Mmax = N / SW + B;

  meta_kernel<<<1, 64, 0, stream>>>(lengths, B, out);

  const int blocks1 = (Mmax + 255) / 256;
  pool_small_kernel<<<blocks1, 256, 0, stream>>>(coord, scores, lengths, B, out);

  const int blocks2 = (Mmax + BM - 1) / BM;
  gemm_kernel<<<blocks2, 256, 0, stream>>>(feat, W, bias, lengths, B, out);
}

// Round 2
// 679.895 us; speedup vs baseline: 1.3085x; 1.3085x over previous
//
#include <hip/hip_runtime.h>

#define CIN 96
#define COUT 192
#define SW 4
#define BM 128       // windows per block
#define KPA 96       // A row stride (shorts); unpadded (conflicts only on 6 cold reads/wave)
#define KPW 104      // Wt row stride (shorts); 16B-multiple, conflict-light for hot B-frag reads

typedef __attribute__((ext_vector_type(8))) short bf16x8;
typedef __attribute__((ext_vector_type(4))) float f32x4;

// fp32 -> bf16 round-to-nearest-even, bit pattern in a short
__device__ __forceinline__ short f2bf(float x) {
  unsigned int u;
  __builtin_memcpy(&u, &x, 4);
  u += 0x7fffu + ((u >> 16) & 1u);
  return (short)(u >> 16);
}

// Fused: windowed mean pool (stride 4) + bf16-MFMA GEMM (M,96)x(96,192) + bias + ReLU
// + coord/scores/batch pooled outputs + lengths_down/offset_down.
__global__ __launch_bounds__(256) void fused_kernel(
    const float* __restrict__ feat, const float* __restrict__ coord,
    const float* __restrict__ scores, const float* __restrict__ W,
    const float* __restrict__ bias, const int* __restrict__ lengths, int B,
    float* __restrict__ out) {
  __shared__ short A_lds[BM * KPA];     // 24576 B, bf16 pooled A tile
  __shared__ short Wt_lds[COUT * KPW];  // 39936 B, bf16 W transposed [n][k]
  __shared__ int s_meta[BM];            // start | (cnt<<28); total LDS = 65024 B

  const int tid = threadIdx.x;
  const long long m0 = (long long)blockIdx.x * BM;

  // Total window count M (wave-uniform scalar loop over B<=8 lengths).
  long long M = 0;
  for (int i = 0; i < B; ++i) M += ((long long)lengths[i] + (SW - 1)) >> 2;

  // Per-window metadata for this block's 128 windows.
  long long startL = 0; int cntL = 0, bfL = 0;
  if (tid < BM) {
    long long m = m0 + tid;
    long long off = 0, woff = 0;
    for (int i = 0; i < B; ++i) {
      long long L = lengths[i];
      long long nw = (L + (SW - 1)) >> 2;
      if (m >= woff && m < woff + nw) {
        long long st = off + (m - woff) * SW;
        long long rem = off + L - st;
        startL = st;
        cntL = (int)(rem < (long long)SW ? rem : (long long)SW);
        bfL = i;
      }
      off += L; woff += nw;
    }
    s_meta[tid] = (int)startL | (cntL << 28);  // start < 2^28 here
  }
  __syncthreads();

  // --- Stage pooled A tile (fp32 accumulate, one bf16 round) ---
  // 128 windows x 24 float4 groups = 3072 tasks, 12/thread; coalesced.
  #pragma unroll 4
  for (int i = 0; i < 12; ++i) {
    int task = tid + 256 * i;
    int w = task / 24;
    int g = task - w * 24;
    int mv = s_meta[w];
    int cw = (int)((unsigned)mv >> 28);
    int st = mv & 0x0FFFFFFF;
    const float* fp = feat + (long long)st * CIN + g * 4;
    float sx = 0.f, sy = 0.f, sz = 0.f, sw2 = 0.f;
    for (int p = 0; p < cw; ++p) {
      float4 v = *(const float4*)(fp + p * CIN);
      sx += v.x; sy += v.y; sz += v.z; sw2 += v.w;
    }
    float inv = cw ? 1.0f / (float)cw : 0.f;
    short4 h;
    h.x = f2bf(sx * inv); h.y = f2bf(sy * inv);
    h.z = f2bf(sz * inv); h.w = f2bf(sw2 * inv);
    *(short4*)&A_lds[w * KPA + g * 4] = h;
  }

  // --- Stage W transposed to bf16: Wt[n][k], n=0..191, k=0..95 ---
  // 192 cols x 12 k-groups(8) = 2304 tasks, 9/thread; global reads coalesced over n.
  #pragma unroll 3
  for (int i = 0; i < 9; ++i) {
    int task = tid + 256 * i;
    int kg = task / COUT;
    int n = task - kg * COUT;
    const float* wp = W + kg * 8 * COUT + n;
    bf16x8 hv;
    #pragma unroll
    for (int j = 0; j < 8; ++j) hv[j] = f2bf(wp[j * COUT]);
    *(bf16x8*)&Wt_lds[n * KPW + kg * 8] = hv;   // byte addr n*208+kg*16, 16B aligned
  }

  // --- Small pooled outputs (independent of LDS; threads 0..127) ---
  if (tid < BM) {
    long long m = m0 + tid;
    if (m < M) {
      float cx = 0.f, cy = 0.f, cz = 0.f, ss = 0.f;
      const float* cp = coord + startL * 3;
      for (int p = 0; p < cntL; ++p) {
        cx += cp[p * 3 + 0]; cy += cp[p * 3 + 1]; cz += cp[p * 3 + 2];
        ss += scores[startL + p];
      }
      float inv = 1.0f / (float)cntL;
      long long o1 = M * (long long)COUT;
      long long o2 = o1 + M * 3;
      long long o3 = o2 + M;
      out[o1 + m * 3 + 0] = cx * inv;
      out[o1 + m * 3 + 1] = cy * inv;
      out[o1 + m * 3 + 2] = cz * inv;
      out[o2 + m] = (float)bfL;   // batch id, exact in fp32
      out[o3 + m] = ss * inv;
    }
  }
  if (blockIdx.x == 0 && tid == 0) {
    long long o4 = M * (long long)(COUT + 3 + 1 + 1);
    long long cum = 0;
    for (int i = 0; i < B; ++i) {
      long long nw = ((long long)lengths[i] + (SW - 1)) >> 2;
      out[o4 + i] = (float)nw;
      cum += nw;
      out[o4 + B + i] = (float)cum;
    }
  }

  __syncthreads();

  // --- MFMA phase: no further barriers ---
  const int wv = tid >> 6;      // wave 0..3 -> rows wv*32 .. wv*32+31
  const int lane = tid & 63;
  const int lm = lane & 15;
  const int quad = lane >> 4;

  // A-fragments in registers: 2 m-tiles x 3 k-steps. Layout A[m=lane&15][k=quad*8+j].
  bf16x8 af[2][3];
  #pragma unroll
  for (int mt = 0; mt < 2; ++mt)
    #pragma unroll
    for (int ks = 0; ks < 3; ++ks)
      af[mt][ks] = *(const bf16x8*)&A_lds[(wv * 32 + mt * 16 + lm) * KPA + ks * 32 + quad * 8];

  f32x4 acc[2][12];
  #pragma unroll
  for (int mt = 0; mt < 2; ++mt)
    #pragma unroll
    for (int nt = 0; nt < 12; ++nt)
      acc[mt][nt] = (f32x4){0.f, 0.f, 0.f, 0.f};

  #pragma unroll
  for (int nt = 0; nt < 12; ++nt) {
    const int nrow = nt * 16 + lm;   // B-fragment: col n = lane&15, k = quad*8+j
    #pragma unroll
    for (int ks = 0; ks < 3; ++ks) {
      bf16x8 bfr = *(const bf16x8*)&Wt_lds[nrow * KPW + ks * 32 + quad * 8];
      acc[0][nt] = __builtin_amdgcn_mfma_f32_16x16x32_bf16(af[0][ks], bfr, acc[0][nt], 0, 0, 0);
      acc[1][nt] = __builtin_amdgcn_mfma_f32_16x16x32_bf16(af[1][ks], bfr, acc[1][nt], 0, 0, 0);
    }
  }

  // --- Epilogue: bias + ReLU. C/D layout: col=lane&15, row=quad*4+reg ---
  #pragma unroll
  for (int nt = 0; nt < 12; ++nt) {
    int col = nt * 16 + lm;
    float bv = bias[col];
    #pragma unroll
    for (int mt = 0; mt < 2; ++mt) {
      long long rbase = m0 + wv * 32 + mt * 16 + quad * 4;
      #pragma unroll
      for (int r = 0; r < 4; ++r) {
        long long m = rbase + r;
        if (m < M) {
          float x = acc[mt][nt][r] + bv;
          out[m * COUT + col] = x > 0.f ? x : 0.f;
        }
      }
    }
  }
}

extern "C" void kernel_launch(void* const* d_in, const int* in_sizes, int n_in,
                              void* d_out, int out_size, void* d_ws, size_t ws_size,
                              hipStream_t stream) {
  const float* feat    = (const float*)d_in[0];
  const float* coord   = (const float*)d_in[1];
  const float* scores  = (const float*)d_in[2];
  const float* W       = (const float*)d_in[3];
  const float* bias    = (const float*)d_in[4];
  const int*   lengths = (const int*)d_in[5];
  float* out = (float*)d_out;

  const int N = in_sizes[2];   // number of points (scores is (N,))
  const int B = in_sizes[5];   // number of batches
  const int Mmax = N / SW + B; // data-independent upper bound on window count

  const int blocks = (Mmax + BM - 1) / BM;
  fused_kernel<<<blocks, 256, 0, stream>>>(feat, coord, scores, W, bias, lengths, B, out);
}